// Round 1
// baseline (251.977 us; speedup 1.0000x reference)
//
#include <hip/hip_runtime.h>
#include <hip/hip_cooperative_groups.h>
#include <math.h>

// Problem constants (T, B, D) = (1024, 16, 1024)
#define T_DIM 1024
#define C_DIM 16384              // B*D columns, each an independent scan
#define TGROUPS 16               // time groups (blocks along T)
#define CGROUPS 16               // column groups (blocks along C)
#define TC (T_DIM / TGROUPS)     // 64 rows per block
#define CC (C_DIM / CGROUPS)     // 1024 cols per block (= 4 KiB row segment)
#define BLOCK_N 1024             // one thread per column in the group

namespace cg = cooperative_groups;

// Exact two-phase scan with grid-wide carry exchange.
// Phase 1: block (tg, cgi) loads its [64 x 1024] tile with 4 KiB-contiguous
//          row segments, computes the zero-initialized local scan per column,
//          writes the chunk-end carry.
// Sync:    cooperative grid sync (device-scope fence included).
// Phase 2: Horner over earlier chunks' carries with beta^64, apply the
//          prefix, store (again 4 KiB-contiguous row segments).
__global__ __launch_bounds__(BLOCK_N, 4)
void pli_scan_coop(const float* __restrict__ x,
                   const float* __restrict__ beta_p,
                   float* __restrict__ out,
                   float* __restrict__ carry) {
    const int tg  = blockIdx.x >> 4;            // time group 0..15
    const int cgi = blockIdx.x & 15;            // col group 0..15
    const int col = (cgi << 10) + threadIdx.x;  // this thread's column

    // beta = sigmoid(beta_param) — broadcast load, cheap
    const float beta = 1.0f / (1.0f + expf(-beta_p[0]));

    const size_t base = (size_t)(tg * TC) * C_DIM + col;
    const float* xp = x + base;

    // Stage the 64-row chunk in registers. Block-level access per row is a
    // dense 4 KiB segment; rows advance sequentially -> near-linear stream.
    float v[TC];
#pragma unroll
    for (int r = 0; r < TC; ++r) {
        v[r] = xp[(size_t)r * C_DIM];
    }

    // Local (zero-initialized) scan: v[r] = sum_{u<=r} beta^(r-u) x[u]
    float run = 0.0f;
#pragma unroll
    for (int r = 0; r < TC; ++r) {
        run = fmaf(run, beta, v[r]);
        v[r] = run;
    }

    // Publish chunk-end carry for this column (contiguous 4 KiB per block)
    carry[tg * C_DIM + col] = run;

    __threadfence();            // device-scope release before the rendezvous
    cg::this_grid().sync();     // cooperative launch required

    // beta^TC via repeated squaring: TC = 64 -> 6 squarings
    float bL = beta;
#pragma unroll
    for (int i = 0; i < 6; ++i) bL *= bL;

    // Prefix at the row before this chunk: Horner over earlier carries.
    // Trip count is wave-uniform (same tg across the block). <= 15 coalesced
    // loads from the 1 MiB carry array (L2-resident after the sync).
    float Y = 0.0f;
    for (int u = 0; u < tg; ++u) {
        Y = fmaf(Y, bL, carry[u * C_DIM + col]);
    }

    // y[s + r] = local[r] + beta^(r+1) * Y_prev
    float m = beta * Y;
    float* op = out + base;
#pragma unroll
    for (int r = 0; r < TC; ++r) {
        op[(size_t)r * C_DIM] = v[r] + m;
        m *= beta;
    }
}

// ---------------------------------------------------------------------------
// Fallback: previous proven single-kernel version (used only if the harness
// workspace is too small for the 1 MiB carry buffer).
#define WAVES 16
#define BLOCK_T (WAVES * 64)
#define L_CHUNK (T_DIM / WAVES)

__global__ __launch_bounds__(BLOCK_T, 4)
void pli_scan_kernel(const float* __restrict__ x,
                     const float* __restrict__ beta_p,
                     float* __restrict__ out) {
    const int lane = threadIdx.x & 63;
    const int w    = threadIdx.x >> 6;
    const int col  = (blockIdx.x << 6) + lane;

    const float beta = 1.0f / (1.0f + expf(-beta_p[0]));

    const size_t base = (size_t)(w * L_CHUNK) * C_DIM + col;
    const float* xp = x + base;

    float v[L_CHUNK];
#pragma unroll
    for (int t = 0; t < L_CHUNK; ++t) v[t] = xp[(size_t)t * C_DIM];

    float run = 0.0f;
#pragma unroll
    for (int t = 0; t < L_CHUNK; ++t) { run = fmaf(run, beta, v[t]); v[t] = run; }

    __shared__ float carry_s[WAVES][64];
    carry_s[w][lane] = run;
    __syncthreads();

    float bL = beta;
#pragma unroll
    for (int i = 0; i < 6; ++i) bL *= bL;

    float Y = 0.0f;
    for (int u = 0; u < w; ++u) Y = fmaf(Y, bL, carry_s[u][lane]);

    float m = beta * Y;
    float* op = out + base;
#pragma unroll
    for (int t = 0; t < L_CHUNK; ++t) {
        op[(size_t)t * C_DIM] = v[t] + m;
        m *= beta;
    }
}

extern "C" void kernel_launch(void* const* d_in, const int* in_sizes, int n_in,
                              void* d_out, int out_size, void* d_ws, size_t ws_size,
                              hipStream_t stream) {
    const float* x      = (const float*)d_in[0];   // [T, B, D] fp32
    const float* beta_p = (const float*)d_in[1];   // scalar fp32
    float* out          = (float*)d_out;           // [T, B, D] fp32

    const size_t carry_bytes = (size_t)TGROUPS * C_DIM * sizeof(float); // 1 MiB

    if (d_ws != nullptr && ws_size >= carry_bytes) {
        float* carry = (float*)d_ws;
        dim3 grid(TGROUPS * CGROUPS);   // 256 blocks = 1 per CU
        dim3 block(BLOCK_N);            // 1024 threads = 16 waves
        void* args[] = { (void*)&x, (void*)&beta_p, (void*)&out, (void*)&carry };
        hipLaunchCooperativeKernel((const void*)pli_scan_coop, grid, block,
                                   args, 0, stream);
    } else {
        dim3 grid(C_DIM / 64);
        dim3 block(BLOCK_T);
        hipLaunchKernelGGL(pli_scan_kernel, grid, block, 0, stream,
                           x, beta_p, out);
    }
}

// Round 2
// 122.172 us; speedup vs baseline: 2.0625x; 2.0625x over previous
//
#include <hip/hip_runtime.h>
#include <math.h>

// Problem constants (T, B, D) = (1024, 16, 1024)
#define T_DIM 1024
#define C_DIM 16384
#define CQ    (C_DIM / 4)        // 4096 float4 column-quads per row
#define BLK   256                // threads per block

__device__ __forceinline__ float sigmoid_beta(const float* bp) {
    return 1.0f / (1.0f + expf(-bp[0]));
}

// ---------------------------------------------------------------------------
// Phase 1: per (time-group, column-quad) running decay-sum over TC rows.
// No per-thread arrays — only a float4 accumulator. Writes chunk-end carry.
template<int TG>
__global__ __launch_bounds__(BLK)
void pli_carry(const float* __restrict__ x,
               const float* __restrict__ beta_p,
               float* __restrict__ carry) {
    constexpr int TC = T_DIM / TG;
    const int nb_c = CQ / BLK;                       // col-blocks per tg
    const int tg = blockIdx.x / nb_c;
    const int q  = (blockIdx.x % nb_c) * BLK + threadIdx.x;

    const float beta = sigmoid_beta(beta_p);
    const float4* xp = (const float4*)x + (size_t)(tg * TC) * CQ + q;

    float4 run = make_float4(0.f, 0.f, 0.f, 0.f);
#pragma unroll
    for (int r = 0; r < TC; ++r) {
        float4 v = xp[(size_t)r * CQ];
        run.x = fmaf(run.x, beta, v.x);
        run.y = fmaf(run.y, beta, v.y);
        run.z = fmaf(run.z, beta, v.z);
        run.w = fmaf(run.w, beta, v.w);
    }
    ((float4*)carry)[(size_t)tg * CQ + q] = run;
}

// ---------------------------------------------------------------------------
// Phase 2: Horner over earlier carries -> prefix Y; re-stream x (L3-resident)
// recomputing the local scan, apply beta^(r+1)*Y, store.
template<int TG>
__global__ __launch_bounds__(BLK)
void pli_apply(const float* __restrict__ x,
               const float* __restrict__ beta_p,
               const float* __restrict__ carry,
               float* __restrict__ out) {
    constexpr int TC = T_DIM / TG;
    const int nb_c = CQ / BLK;
    const int tg = blockIdx.x / nb_c;
    const int q  = (blockIdx.x % nb_c) * BLK + threadIdx.x;

    const float beta = sigmoid_beta(beta_p);

    // beta^TC by repeated squaring (TC is a power of two)
    float bL = beta;
    for (int i = TC; i > 1; i >>= 1) bL *= bL;

    // Prefix at the row before this chunk: Y = sum_u carry[u] * bL^(tg-1-u)
    const float4* cp = (const float4*)carry + q;
    float4 Y = make_float4(0.f, 0.f, 0.f, 0.f);
    for (int u = 0; u < tg; ++u) {                   // wave-uniform trip count
        float4 c = cp[(size_t)u * CQ];
        Y.x = fmaf(Y.x, bL, c.x);
        Y.y = fmaf(Y.y, bL, c.y);
        Y.z = fmaf(Y.z, bL, c.z);
        Y.w = fmaf(Y.w, bL, c.w);
    }

    float4 m = make_float4(beta * Y.x, beta * Y.y, beta * Y.z, beta * Y.w);

    const float4* xp = (const float4*)x   + (size_t)(tg * TC) * CQ + q;
    float4*       op = (float4*)out       + (size_t)(tg * TC) * CQ + q;

    float4 run = make_float4(0.f, 0.f, 0.f, 0.f);
#pragma unroll
    for (int r = 0; r < TC; ++r) {
        float4 v = xp[(size_t)r * CQ];
        run.x = fmaf(run.x, beta, v.x);
        run.y = fmaf(run.y, beta, v.y);
        run.z = fmaf(run.z, beta, v.z);
        run.w = fmaf(run.w, beta, v.w);
        float4 o;
        o.x = run.x + m.x;
        o.y = run.y + m.y;
        o.z = run.z + m.z;
        o.w = run.w + m.w;
        op[(size_t)r * CQ] = o;
        m.x *= beta; m.y *= beta; m.z *= beta; m.w *= beta;
    }
}

// ---------------------------------------------------------------------------
// Fallback: proven single-kernel version (only if workspace is too small).
#define WAVES 16
#define BLOCK_T (WAVES * 64)
#define L_CHUNK (T_DIM / WAVES)

__global__ __launch_bounds__(BLOCK_T, 4)
void pli_scan_kernel(const float* __restrict__ x,
                     const float* __restrict__ beta_p,
                     float* __restrict__ out) {
    const int lane = threadIdx.x & 63;
    const int w    = threadIdx.x >> 6;
    const int col  = (blockIdx.x << 6) + lane;

    const float beta = 1.0f / (1.0f + expf(-beta_p[0]));

    const size_t base = (size_t)(w * L_CHUNK) * C_DIM + col;
    const float* xp = x + base;

    float v[L_CHUNK];
#pragma unroll
    for (int t = 0; t < L_CHUNK; ++t) v[t] = xp[(size_t)t * C_DIM];

    float run = 0.0f;
#pragma unroll
    for (int t = 0; t < L_CHUNK; ++t) { run = fmaf(run, beta, v[t]); v[t] = run; }

    __shared__ float carry_s[WAVES][64];
    carry_s[w][lane] = run;
    __syncthreads();

    float bL = beta;
#pragma unroll
    for (int i = 0; i < 6; ++i) bL *= bL;

    float Y = 0.0f;
    for (int u = 0; u < w; ++u) Y = fmaf(Y, bL, carry_s[u][lane]);

    float m = beta * Y;
    float* op = out + base;
#pragma unroll
    for (int t = 0; t < L_CHUNK; ++t) {
        op[(size_t)t * C_DIM] = v[t] + m;
        m *= beta;
    }
}

// ---------------------------------------------------------------------------
extern "C" void kernel_launch(void* const* d_in, const int* in_sizes, int n_in,
                              void* d_out, int out_size, void* d_ws, size_t ws_size,
                              hipStream_t stream) {
    const float* x      = (const float*)d_in[0];   // [T, B, D] fp32
    const float* beta_p = (const float*)d_in[1];   // scalar fp32
    float* out          = (float*)d_out;           // [T, B, D] fp32

    const size_t need64 = (size_t)64 * C_DIM * sizeof(float);  // 4 MiB
    const size_t need16 = (size_t)16 * C_DIM * sizeof(float);  // 1 MiB

    if (d_ws != nullptr && ws_size >= need64) {
        // TG=64: TC=16, 1024 blocks -> 16 waves/CU each phase
        float* carry = (float*)d_ws;
        dim3 grid(64 * (CQ / BLK));
        dim3 block(BLK);
        hipLaunchKernelGGL((pli_carry<64>), grid, block, 0, stream, x, beta_p, carry);
        hipLaunchKernelGGL((pli_apply<64>), grid, block, 0, stream, x, beta_p, carry, out);
    } else if (d_ws != nullptr && ws_size >= need16) {
        // TG=16: TC=64, 256 blocks
        float* carry = (float*)d_ws;
        dim3 grid(16 * (CQ / BLK));
        dim3 block(BLK);
        hipLaunchKernelGGL((pli_carry<16>), grid, block, 0, stream, x, beta_p, carry);
        hipLaunchKernelGGL((pli_apply<16>), grid, block, 0, stream, x, beta_p, carry, out);
    } else {
        dim3 grid(C_DIM / 64);
        dim3 block(BLOCK_T);
        hipLaunchKernelGGL(pli_scan_kernel, grid, block, 0, stream, x, beta_p, out);
    }
}

// Round 5
// 115.885 us; speedup vs baseline: 2.1744x; 1.0543x over previous
//
#include <hip/hip_runtime.h>
#include <math.h>

// Problem constants (T, B, D) = (1024, 16, 1024)
#define T_DIM 1024
#define C_DIM 16384            // B*D columns, each an independent scan
#define WAVES 16               // waves per block
#define BLOCK_T (WAVES * 64)   // 1024 threads
#define L_CHUNK (T_DIM / WAVES) // 64 rows per wave

// Single-pass scan: each block owns 64 columns (one lane per column), T is
// split across the 16 waves. Load chunk to registers -> local Horner scan ->
// LDS carry exchange -> per-wave prefix -> apply + store.
// Exactly one read + one write per element (128 MiB total).
// Streams are touched once -> nontemporal hints skip cache allocation.
__global__ __launch_bounds__(BLOCK_T, 4)
void pli_scan_kernel(const float* __restrict__ x,
                     const float* __restrict__ beta_p,
                     float* __restrict__ out) {
    const int lane = threadIdx.x & 63;
    const int w    = threadIdx.x >> 6;           // wave id = T-chunk id
    const int col  = (blockIdx.x << 6) + lane;   // this lane's column

    // beta = sigmoid(beta_param) — broadcast load, cheap
    const float beta = 1.0f / (1.0f + expf(-beta_p[0]));

    const size_t base = (size_t)(w * L_CHUNK) * C_DIM + col;
    const float* xp = x + base;

    // Stage the chunk in registers: 64 independent coalesced loads
    // (wave footprint 256 B = 4 full cache lines per instruction).
    float v[L_CHUNK];
#pragma unroll
    for (int t = 0; t < L_CHUNK; ++t) {
        v[t] = __builtin_nontemporal_load(&xp[(size_t)t * C_DIM]);
    }

    // Local (zero-initialized) scan in place: v[t] = sum_{u<=t} beta^(t-u) x[u]
    float run = 0.0f;
#pragma unroll
    for (int t = 0; t < L_CHUNK; ++t) {
        run = fmaf(run, beta, v[t]);
        v[t] = run;
    }

    // Exchange per-chunk carries (local scan value at chunk end)
    __shared__ float carry[WAVES][64];
    carry[w][lane] = run;
    __syncthreads();

    // beta^L via repeated squaring: L = 64 -> 6 squarings
    float bL = beta;
#pragma unroll
    for (int i = 0; i < 6; ++i) bL *= bL;

    // Prefix for this chunk: Y = full-scan value at row (w*L - 1).
    // Horner over earlier chunks' carries; wave-uniform trip count.
    float Y = 0.0f;
    for (int u = 0; u < w; ++u) {
        Y = fmaf(Y, bL, carry[u][lane]);
    }

    // y[s+t] = local[t] + beta^(t+1) * Y_prev
    float m = beta * Y;
    float* op = out + base;
#pragma unroll
    for (int t = 0; t < L_CHUNK; ++t) {
        __builtin_nontemporal_store(v[t] + m, &op[(size_t)t * C_DIM]);
        m *= beta;
    }
}

extern "C" void kernel_launch(void* const* d_in, const int* in_sizes, int n_in,
                              void* d_out, int out_size, void* d_ws, size_t ws_size,
                              hipStream_t stream) {
    const float* x      = (const float*)d_in[0];   // [T, B, D] fp32
    const float* beta_p = (const float*)d_in[1];   // scalar fp32
    float* out          = (float*)d_out;           // [T, B, D] fp32

    dim3 grid(C_DIM / 64);   // 256 blocks, one per CU
    dim3 block(BLOCK_T);     // 1024 threads = 16 waves
    hipLaunchKernelGGL(pli_scan_kernel, grid, block, 0, stream, x, beta_p, out);
}

// Round 6
// 109.564 us; speedup vs baseline: 2.2998x; 1.0577x over previous
//
#include <hip/hip_runtime.h>
#include <math.h>

// Problem constants (T, B, D) = (1024, 16, 1024)
#define T_DIM 1024
#define C_DIM 16384            // B*D columns, each an independent scan
#define WAVES 16               // waves per block
#define BLOCK_T (WAVES * 64)   // 1024 threads
#define L_CHUNK (T_DIM / WAVES) // 64 rows per wave

// Each block: 64 columns (one lane per column), T split across 16 waves.
// Single pass: load chunk to regs -> local scan -> LDS carry exchange ->
// per-wave prefix -> apply + store. One read + one write per element.
// NOTE: nontemporal load/store hints were tried (round 5) and REGRESSED
// ~5 us — L2 allocation helps merge adjacent blocks' 256 B column windows
// into full-rate HBM streams. Keep plain cached accesses.
__global__ __launch_bounds__(BLOCK_T, 4)
void pli_scan_kernel(const float* __restrict__ x,
                     const float* __restrict__ beta_p,
                     float* __restrict__ out) {
    const int lane = threadIdx.x & 63;
    const int w    = threadIdx.x >> 6;           // wave id = T-chunk id
    const int col  = (blockIdx.x << 6) + lane;   // this lane's column

    // beta = sigmoid(beta_param), computed per-thread (broadcast load, cheap)
    const float beta = 1.0f / (1.0f + expf(-beta_p[0]));

    const size_t base = (size_t)(w * L_CHUNK) * C_DIM + col;
    const float* xp = x + base;

    // Stage the chunk in registers: 64 independent coalesced loads (256B/instr)
    float v[L_CHUNK];
#pragma unroll
    for (int t = 0; t < L_CHUNK; ++t) {
        v[t] = xp[(size_t)t * C_DIM];
    }

    // Local (zero-initialized) scan in place: v[t] = sum_{u<=t} beta^(t-u) x[u]
    float run = 0.0f;
#pragma unroll
    for (int t = 0; t < L_CHUNK; ++t) {
        run = fmaf(run, beta, v[t]);
        v[t] = run;
    }

    // Exchange per-chunk carries (value of local scan at chunk end)
    __shared__ float carry[WAVES][64];
    carry[w][lane] = run;
    __syncthreads();

    // beta^L via repeated squaring: L=64 -> 6 squarings
    float bL = beta;
#pragma unroll
    for (int i = 0; i < 6; ++i) bL *= bL;

    // Prefix for this chunk: Y_prev = full scan value at row (w*L - 1)
    // Y_v = carry_v + beta^L * Y_{v-1}; iterate v = 0..w-1 (wave-uniform count)
    float Y = 0.0f;
    for (int u = 0; u < w; ++u) {
        Y = fmaf(Y, bL, carry[u][lane]);
    }

    // y[s+t] = local[t] + beta^(t+1) * Y_prev
    float m = beta * Y;
    float* op = out + base;
#pragma unroll
    for (int t = 0; t < L_CHUNK; ++t) {
        op[(size_t)t * C_DIM] = v[t] + m;
        m *= beta;
    }
}

extern "C" void kernel_launch(void* const* d_in, const int* in_sizes, int n_in,
                              void* d_out, int out_size, void* d_ws, size_t ws_size,
                              hipStream_t stream) {
    const float* x      = (const float*)d_in[0];   // [T, B, D] fp32
    const float* beta_p = (const float*)d_in[1];   // scalar fp32
    float* out          = (float*)d_out;           // [T, B, D] fp32

    dim3 grid(C_DIM / 64);   // 256 blocks, one per CU
    dim3 block(BLOCK_T);     // 1024 threads = 16 waves
    hipLaunchKernelGGL(pli_scan_kernel, grid, block, 0, stream, x, beta_p, out);
}